// Round 5
// baseline (534.091 us; speedup 1.0000x reference)
//
#include <hip/hip_runtime.h>
#include <cmath>

// DTASNN embedding via i8 QUAD-limb MFMA implicit conv.
//
// R19 vs R18 (405us fused kernel; FETCH ~505MB invariant to fence/poll/store
// changes => NOT comms traffic. Volume matches "Wp (590KB) re-fetched from
// HBM by every block every step": L2 capacity thrash. The fused kernel keeps
// all 5 event time-slices in flight with step skew; if workgroup->XCD
// placement isn't the assumed bid%8 round-robin (undefined by HIP), each XCD
// sees ~8 batches x 2-3 skewed steps x 262KB + Wp > 4MB L2 -> event
// streaming continuously evicts Wp. WRITE=0.75xFETCH = victim traffic,
// same symptom):
//  - evb event loads -> NON-TEMPORAL (__builtin_nontemporal_load): events
//    are consumed once per step; nt stops them allocating/evicting in L2,
//    leaving Wp resident. outF final stores -> nontemporal likewise.
//  - Everything else IDENTICAL to R18 (single-variable experiment):
//    2-lane poll, dense sc0sc1 spike publish, halo sc0sc1 loads, LIF state
//    in VGPRs, zero cache-maintenance instructions.
// Arithmetic identical -> bit-exact.
//
// ws: flags 1KB | sA @16M 2MB | sB 2MB | evb 10.5MB | Wp 576KB | tabs

typedef __attribute__((ext_vector_type(4))) int intx4;

#define HW 64
#define TT 5
#define PLANE 4096
#define CSTR 144                  // U px stride bytes (128 ch + 16 pad): odd 9 quads
#define USIZE (4 * 66 * CSTR)     // 38016 B
#define WPL 147456                // per-limb Wp bytes: 9 tap * 2 ks * 4 q * 128 o * 16

// ---- prep: weight limbs + bias/threshold tables + flag reset ----
// Wp[limb]: addr = ((tap*2+ks)*4 + q)*2048 + o*16 + j ; o = g*16+i,
// i<8 -> cur row co=g*8+i, i>=8 -> gate row 64+co; c = ks*64 + q*16 + j.
__global__ __launch_bounds__(256) void prep_w(
    const float* __restrict__ w_in, const float* __restrict__ w_gate,
    const float* __restrict__ b_in, const float* __restrict__ b_gate,
    const float* __restrict__ tdec,
    signed char* __restrict__ Wp, float* __restrict__ tabs,
    unsigned* __restrict__ flags)
{
  const int idx = blockIdx.x * 256 + threadIdx.x;
  if (idx < 256) {                           // p2p flags -> coherent point
    unsigned z = 0;
    unsigned* fp = flags + idx;
    asm volatile("global_store_dword %0, %1, off sc0 sc1"
                 :: "v"(fp), "v"(z) : "memory");
  }
  if (idx < 9216) {
    const int o   = idx & 127;
    const int q   = (idx >> 7) & 3;
    const int ks  = (idx >> 9) & 1;
    const int tap = idx >> 10;               // 0..8
    const int g = o >> 4, i = o & 15;
    const int row = (i >> 3) * 64 + g * 8 + (i & 7);
    int p1[4], p2[4], p3[4], p4[4];
#pragma unroll
    for (int wd = 0; wd < 4; ++wd) {
      int v1 = 0, v2 = 0, v3 = 0, v4 = 0;
#pragma unroll
      for (int jb = 0; jb < 4; ++jb) {
        const int j = wd * 4 + jb;
        const int c = ks * 64 + q * 16 + j;
        const float w = (c < 64) ? w_in[(row * 64 + c) * 9 + tap]
                                 : w_gate[(row * 64 + (c - 64)) * 9 + tap];
        float a1 = fminf(fmaxf(rintf(w * 256.f), -127.f), 127.f);
        float r1 = w * 256.f - a1;              // in [-0.5, 0.5]
        float a2 = rintf(r1 * 128.f);
        float r2 = r1 * 128.f - a2;
        float a3 = rintf(r2 * 128.f);
        float r3 = r2 * 128.f - a3;
        float a4 = rintf(r3 * 128.f);
        v1 |= ((int)a1 & 255) << (8 * jb);
        v2 |= ((int)a2 & 255) << (8 * jb);
        v3 |= ((int)a3 & 255) << (8 * jb);
        v4 |= ((int)a4 & 255) << (8 * jb);
      }
      p1[wd] = v1; p2[wd] = v2; p3[wd] = v3; p4[wd] = v4;
    }
    intx4* d = (intx4*)(Wp + (size_t)idx * 16);
    d[0]                          = intx4{p1[0], p1[1], p1[2], p1[3]};
    *(intx4*)((char*)d + WPL)     = intx4{p2[0], p2[1], p2[2], p2[3]};
    *(intx4*)((char*)d + 2 * WPL) = intx4{p3[0], p3[1], p3[2], p3[3]};
    *(intx4*)((char*)d + 3 * WPL) = intx4{p4[0], p4[1], p4[2], p4[3]};
  }
  if (idx < 448) {                           // tabs: bc|bg [128], th [5][64]
    if (idx < 128) tabs[idx] = b_in[idx] + b_gate[idx];
    else {
      const int t = (idx - 128) >> 6, co = (idx - 128) & 63;
      tabs[idx] = powf(tdec[co], (float)t);  // THRESH=1.0
    }
  }
}

// ---- prep: events fp32 [b][tp][c][h][w] -> i8 ch-minor [b][tp][h][w][c] ----
__global__ __launch_bounds__(256) void prep_ev(
    const float* __restrict__ ev, signed char* __restrict__ evb)
{
  const int row  = blockIdx.x * 4 + (threadIdx.x >> 6);  // 0..2559 = (b,tp,h)
  const int w    = threadIdx.x & 63;
  const int b  = row / (TT * HW);
  const int rm = row % (TT * HW);
  const int tp = rm / HW;
  const int h  = rm % HW;
  const float* src = ev + ((size_t)(b * TT + tp) * 64) * PLANE + h * HW + w;
  signed char* dst = evb + ((size_t)((b * TT + tp) * PLANE + h * HW + w)) * 64;
#pragma unroll
  for (int k = 0; k < 8; ++k) {
    unsigned long long pk = 0;
#pragma unroll
    for (int j = 0; j < 8; ++j)
      pk |= (src[(size_t)(k * 8 + j) * PLANE] != 0.f)
              ? (1ull << (8 * j)) : 0ull;
    *(unsigned long long*)(dst + k * 8) = pk;
  }
}

// ---- fused persistent kernel: all 5 steps, LIF state in VGPRs ----
__global__ __launch_bounds__(1024, 4) void snn_all(
    const signed char* __restrict__ evb,
    const signed char* __restrict__ Wp,
    const float*       __restrict__ tabs,
    signed char*                    sA,     // spike ping-pong (ch-minor i8)
    signed char*                    sB,
    unsigned*                       flags,  // [256] completed-step counters
    float*             __restrict__ outF)   // d_out [b][co][h][w] fp32
{
  __shared__ signed char U[USIZE];  // [row4][col66][c144]: rows r0-1..r0+2

  const int tid = threadIdx.x;               // 0..1023
  const int bid = blockIdx.x;
  const int b   = bid & 7;                   // batch -> XCD (round-robin, perf)
  const int rr  = bid >> 3;                  // row-pair 0..31
  const int r0  = rr * 2;                    // img rows r0, r0+1

  const int lane = tid & 63;
  const int g    = (tid >> 6) & 7;           // o-group 0..7
  const int hf   = tid >> 9;                 // tile-half 0/1 (img row r0+hf)
  const int ln   = lane & 15;                // = A's m = B's n (px col in tile)
  const int q    = lane >> 4;                // k-group 0..3

  // staging: 4 rows x 64 cols x 4 x 32B-chunks (sch<2: events, sch>=2: spikes)
  const int srow = tid >> 8;
  const int scol = (tid >> 2) & 63;
  const int sch  = tid & 3;
  const int sr   = r0 + srow - 1;
  const bool svalid  = (sr >= 0) && (sr < HW);
  const bool evldr   = svalid && (sch < 2);
  const bool haloldr = svalid && (sch >= 2) && (srow == 0 || srow == 3);
  signed char* du = U + (srow * 66 + scol + 1) * CSTR + sch * 32;

  // ---- zero U once: halo col 0/65 + oob rows stay 0 forever (SAME pad) ----
  for (int i = tid; i < USIZE / 16; i += 1024) ((intx4*)U)[i] = intx4{0, 0, 0, 0};

  // issue t=0 event loads (non-temporal: consumed once, keep out of L2)
  intx4 st0 = intx4{0,0,0,0}, st1 = intx4{0,0,0,0};
  if (evldr) {
    const signed char* gs = evb
        + ((size_t)((b * TT + (TT - 1)) * PLANE + sr * HW + scol)) * 64 + sch * 32;
    st0 = __builtin_nontemporal_load((const intx4*)gs);
    st1 = __builtin_nontemporal_load((const intx4*)(gs + 16));
  }

  const int laneB = ln * CSTR + q * 16;
  const signed char* wlane = Wp + q * 2048 + (g * 16 + ln) * 16;
  const int co0 = g * 8 + (q & 1) * 4;
  const float4 bc4 = *(const float4*)&tabs[co0];
  const float4 bg4 = *(const float4*)&tabs[64 + co0];
  const int hh = r0 + hf;

  // dense spike storer role (512 threads): one 16B chunk of own rows' spikes
  const int spx  = tid >> 2;                 // 0..127 (valid when tid<512)
  const int sprw = spx >> 6;                 // 0,1 -> own rows r0+sprw
  const int spcl = spx & 63;
  const int spch = (tid & 3) * 16;
  const signed char* spu = U + ((1 + sprw) * 66 + spcl + 1) * CSTR + 64 + spch;
  const size_t      spgo = ((size_t)((b * HW + r0 + sprw) * HW + spcl)) * 64 + spch;

  // LIF state lives in registers: thread-private across all 5 steps
  float vmr[4][4], ocr[4][4];
#pragma unroll
  for (int tt = 0; tt < 4; ++tt)
#pragma unroll
    for (int r = 0; r < 4; ++r) { vmr[tt][r] = 0.f; ocr[tt][r] = 0.f; }

  __syncthreads();   // U zero complete

  for (int t = 0; t < TT; ++t) {
    // ---- wait for neighbors' step t-1 spikes: 2 polling LANES only ----
    if (t > 0) {
      if (tid < 2) {
        const bool need = tid ? (rr < 31) : (rr > 0);
        if (need) {
          const unsigned* fp = flags + (tid ? bid + 8 : bid - 8);
          for (;;) {
            unsigned fv;
            asm volatile("global_load_dword %0, %1, off sc0 sc1\n\t"
                         "s_waitcnt vmcnt(0)"
                         : "=v"(fv) : "v"(fp) : "memory");
            if (fv >= (unsigned)t) break;
            __builtin_amdgcn_s_sleep(8);
          }
        }
      }
      __syncthreads();   // neighbors' spikes now safe to read
      if (haloldr) {     // halo rows (srow 0/3) from coherent point
        const signed char* ss = (t & 1) ? sB : sA;
        const signed char* gs = ss
            + ((size_t)((b * HW + sr) * HW + scol)) * 64 + (sch - 2) * 32;
        intx4 h0, h1;
        asm volatile("global_load_dwordx4 %0, %2, off sc0 sc1\n\t"
                     "global_load_dwordx4 %1, %2, off offset:16 sc0 sc1\n\t"
                     "s_waitcnt vmcnt(0)"
                     : "=v"(h0), "=v"(h1) : "v"(gs) : "memory");
        *(intx4*)du        = h0;
        *(intx4*)(du + 16) = h1;
      }
    }
    if (evldr) { *(intx4*)du = st0; *(intx4*)(du + 16) = st1; }
    const float4 th4 = *(const float4*)&tabs[128 + t * 64 + co0];
    __syncthreads();   // U ready

    // ---- MFMA: acc[limb][tt] (i32, exact), tile (hf*4+tt), K=128 = 2 ks x 64
    intx4 acc1[4], acc2[4], acc3[4], acc4[4];
#pragma unroll
    for (int tt = 0; tt < 4; ++tt) {
      acc1[tt] = intx4{0,0,0,0}; acc2[tt] = intx4{0,0,0,0};
      acc3[tt] = intx4{0,0,0,0}; acc4[tt] = intx4{0,0,0,0};
    }
    for (int tap = 0; tap < 9; ++tap) {
      const int kh = (tap * 11) >> 5;        // tap/3
      const int kw = tap - 3 * kh;
#pragma unroll
      for (int ks = 0; ks < 2; ++ks) {
        const signed char* wp = wlane + (tap * 2 + ks) * 8192;
        const intx4 A1 = *(const intx4*)(wp);
        const intx4 A2 = *(const intx4*)(wp + WPL);
        const intx4 A3 = *(const intx4*)(wp + 2 * WPL);
        const intx4 A4 = *(const intx4*)(wp + 3 * WPL);
        const signed char* ub = U + (hf + kh) * (66 * CSTR) + kw * CSTR + ks * 64 + laneB;
#pragma unroll
        for (int tt = 0; tt < 4; ++tt) {
          const intx4 B = *(const intx4*)(ub + tt * (16 * CSTR));
          acc1[tt] = __builtin_amdgcn_mfma_i32_16x16x64_i8(A1, B, acc1[tt], 0, 0, 0);
          acc2[tt] = __builtin_amdgcn_mfma_i32_16x16x64_i8(A2, B, acc2[tt], 0, 0, 0);
          acc3[tt] = __builtin_amdgcn_mfma_i32_16x16x64_i8(A3, B, acc3[tt], 0, 0, 0);
          acc4[tt] = __builtin_amdgcn_mfma_i32_16x16x64_i8(A4, B, acc4[tt], 0, 0, 0);
        }
      }
    }
    __syncthreads();   // all U reads done (epilogue rewrites U spike channels)

    // ---- LIF epilogue, state in regs. D: col=lane&15, row(o')=q*4+reg.
    // lane l (q<2: cur rows) <-> l^32 (gate rows, same co,px).
    const bool tL = (t == TT - 1);
#pragma unroll
    for (int tt = 0; tt < 4; ++tt) {
      const int col = tt * 16 + ln;
      float mine[4];
#pragma unroll
      for (int r = 0; r < 4; ++r)
        mine[r] = fmaf((float)acc1[tt][r], 0x1p-8f,
                  fmaf((float)acc2[tt][r], 0x1p-15f,
                  fmaf((float)acc3[tt][r], 0x1p-22f,
                       (float)acc4[tt][r] * 0x1p-29f)));
      float other[4];
#pragma unroll
      for (int r = 0; r < 4; ++r) other[r] = __shfl_xor(mine[r], 32, 64);
      if (q < 2) {
        uint fm = 0;
#pragma unroll
        for (int r = 0; r < 4; ++r) {
          const float cur  = mine[r] + (&bc4.x)[r];
          const float gp   = other[r] + (&bg4.x)[r];
          const float gate = 1.f / (1.f + expf(-gp));
          const float v    = gate * vmr[tt][r] + cur;   // vmem = gate*vmem + cur
          const bool fired = (v >= (&th4.x)[r]);        // heaviside(v - thresh_t)
          vmr[tt][r] = fired ? 0.f : v;                 // hard reset to VRESET=0
          ocr[tt][r] += fired ? 1.f : 0.f;
          fm |= fired ? (1u << (8 * r)) : 0u;
        }
        if (!tL) {
          // own spikes straight into U (contiguous spike bytes of own rows)
          *(uint*)(U + ((1 + hf) * 66 + col + 1) * CSTR + 64 + co0) = fm;
        } else {
          // final: mean over T=5, scatter to d_out's [b][co][h][w] (streaming)
#pragma unroll
          for (int r = 0; r < 4; ++r)
            __builtin_nontemporal_store(ocr[tt][r] * 0.2f,
                &outF[((size_t)((b * 64 + co0 + r) * HW + hh)) * HW + col]);
        }
      }
    }

    if (!tL) {
      __syncthreads();   // U spike bytes visible to storer threads
      if (tid < 512) {   // dense, fully-coalesced spike publish (8KB/block)
        signed char* sd = (t & 1) ? sA : sB;
        intx4 v = *(const intx4*)spu;        // ds_read_b128
        signed char* gp = sd + spgo;
        asm volatile("global_store_dwordx4 %0, %1, off sc0 sc1"
                     :: "v"(gp), "v"(v) : "memory");
      }
      asm volatile("s_waitcnt vmcnt(0)" ::: "memory");
      __syncthreads();   // every thread's stores drained
      if (tid == 0) {
        unsigned nf = (unsigned)(t + 1);
        unsigned* fp = flags + bid;
        asm volatile("global_store_dword %0, %1, off sc0 sc1"
                     :: "v"(fp), "v"(nf) : "memory");
      }
      // prefetch next step's events (non-temporal: keep out of L2)
      if (evldr) {
        const signed char* gs = evb
            + ((size_t)((b * TT + (TT - 2 - t)) * PLANE + sr * HW + scol)) * 64
            + sch * 32;
        st0 = __builtin_nontemporal_load((const intx4*)gs);
        st1 = __builtin_nontemporal_load((const intx4*)(gs + 16));
      }
    }
  }
}

extern "C" void kernel_launch(void* const* d_in, const int* in_sizes, int n_in,
                              void* d_out, int out_size, void* d_ws, size_t ws_size,
                              hipStream_t stream) {
  const float* events = (const float*)d_in[0];
  const float* w_in   = (const float*)d_in[1];
  const float* b_in   = (const float*)d_in[2];
  const float* w_gate = (const float*)d_in[3];
  const float* b_gate = (const float*)d_in[4];
  const float* tdec   = (const float*)d_in[5];
  float* out = (float*)d_out;

  char* base = (char*)d_ws;
  unsigned*    flags = (unsigned*)base;                 //      1,024 B
  signed char* sA    = (signed char*)(base + 16777216); //  2,097,152 B (t0 never read)
  signed char* sB    = (signed char*)(base + 18874368); //  2,097,152 B
  signed char* evb   = (signed char*)(base + 20971520); // 10,485,760 B
  signed char* Wp    = (signed char*)(base + 31457280); //    589,824 B (4 limbs)
  float*       tabs  = (float*)(base + 32047104);       //      1,792 B

  hipLaunchKernelGGL(prep_w,  dim3(36),  dim3(256), 0, stream,
                     w_in, w_gate, b_in, b_gate, tdec, Wp, tabs, flags);
  hipLaunchKernelGGL(prep_ev, dim3(640), dim3(256), 0, stream, events, evb);

  void* args[] = {(void*)&evb, (void*)&Wp, (void*)&tabs,
                  (void*)&sA, (void*)&sB, (void*)&flags, (void*)&out};
  hipLaunchCooperativeKernel(reinterpret_cast<const void*>(snn_all),
                             dim3(256), dim3(1024), args, 0, stream);
}

// Round 6
// 335.932 us; speedup vs baseline: 1.5899x; 1.5899x over previous
//
#include <hip/hip_runtime.h>
#include <cmath>

// DTASNN embedding via i8 QUAD-limb MFMA implicit conv.
//
// R20 vs R19 (405us fused kernel; FETCH ~500MB / WRITE ~378MB proven to be
// FIXED-COUNT (31ms outlier: +16% FETCH at 76x duration -> not poll traffic),
// SYMMETRIC R+W, invariant to fences/poll/store/nt changes => SCRATCH, i.e.
// register spills. VGPR_Count=64 every round = arch-VGPR cap at
// __launch_bounds__(1024,4): 4 waves/EU -> 64 arch regs (acc lives in the
// AGPR half). Fused kernel's persistent vmr/ocr/prefetch state needs ~90+
// arch regs -> ~30 spilled, restored+saved every step = ~400MB each way.
// R14's per-step kernel fit in 64 -> no spill -> its sane counters):
//  - Blocks 1024 -> 512 threads (8 waves = 2 waves/EU -> 256 VGPR/wave).
//    Each wave owns BOTH hf halves: hf is now a loop. acc stays 64 live
//    (hf-outer); epilogue per hf is register-only compute into
//    vmr/ocr[2][4][4] + fmr[2][4]; U spike-writes deferred until after the
//    all-U-reads barrier (same hazard discipline as before).
//  - Staging rescaled: 512 = srow(4) x scol(64) x sc2(2), 32B chunks.
//    Spike publish storer role unchanged (all 512 threads, 16B each).
//  - Comms protocol IDENTICAL to R18/R19 (2-lane poll, sc0sc1 spike
//    publish + halo loads + flags, zero cache-maintenance).
// Arithmetic identical -> bit-exact.
//
// ws: flags 1KB | sA @16M 2MB | sB 2MB | evb 10.5MB | Wp 576KB | tabs

typedef __attribute__((ext_vector_type(4))) int intx4;

#define HW 64
#define TT 5
#define PLANE 4096
#define CSTR 144                  // U px stride bytes (128 ch + 16 pad): odd 9 quads
#define USIZE (4 * 66 * CSTR)     // 38016 B
#define WPL 147456                // per-limb Wp bytes: 9 tap * 2 ks * 4 q * 128 o * 16

// ---- prep: weight limbs + bias/threshold tables + flag reset ----
// Wp[limb]: addr = ((tap*2+ks)*4 + q)*2048 + o*16 + j ; o = g*16+i,
// i<8 -> cur row co=g*8+i, i>=8 -> gate row 64+co; c = ks*64 + q*16 + j.
__global__ __launch_bounds__(256) void prep_w(
    const float* __restrict__ w_in, const float* __restrict__ w_gate,
    const float* __restrict__ b_in, const float* __restrict__ b_gate,
    const float* __restrict__ tdec,
    signed char* __restrict__ Wp, float* __restrict__ tabs,
    unsigned* __restrict__ flags)
{
  const int idx = blockIdx.x * 256 + threadIdx.x;
  if (idx < 256) {                           // p2p flags -> coherent point
    unsigned z = 0;
    unsigned* fp = flags + idx;
    asm volatile("global_store_dword %0, %1, off sc0 sc1"
                 :: "v"(fp), "v"(z) : "memory");
  }
  if (idx < 9216) {
    const int o   = idx & 127;
    const int q   = (idx >> 7) & 3;
    const int ks  = (idx >> 9) & 1;
    const int tap = idx >> 10;               // 0..8
    const int g = o >> 4, i = o & 15;
    const int row = (i >> 3) * 64 + g * 8 + (i & 7);
    int p1[4], p2[4], p3[4], p4[4];
#pragma unroll
    for (int wd = 0; wd < 4; ++wd) {
      int v1 = 0, v2 = 0, v3 = 0, v4 = 0;
#pragma unroll
      for (int jb = 0; jb < 4; ++jb) {
        const int j = wd * 4 + jb;
        const int c = ks * 64 + q * 16 + j;
        const float w = (c < 64) ? w_in[(row * 64 + c) * 9 + tap]
                                 : w_gate[(row * 64 + (c - 64)) * 9 + tap];
        float a1 = fminf(fmaxf(rintf(w * 256.f), -127.f), 127.f);
        float r1 = w * 256.f - a1;              // in [-0.5, 0.5]
        float a2 = rintf(r1 * 128.f);
        float r2 = r1 * 128.f - a2;
        float a3 = rintf(r2 * 128.f);
        float r3 = r2 * 128.f - a3;
        float a4 = rintf(r3 * 128.f);
        v1 |= ((int)a1 & 255) << (8 * jb);
        v2 |= ((int)a2 & 255) << (8 * jb);
        v3 |= ((int)a3 & 255) << (8 * jb);
        v4 |= ((int)a4 & 255) << (8 * jb);
      }
      p1[wd] = v1; p2[wd] = v2; p3[wd] = v3; p4[wd] = v4;
    }
    intx4* d = (intx4*)(Wp + (size_t)idx * 16);
    d[0]                          = intx4{p1[0], p1[1], p1[2], p1[3]};
    *(intx4*)((char*)d + WPL)     = intx4{p2[0], p2[1], p2[2], p2[3]};
    *(intx4*)((char*)d + 2 * WPL) = intx4{p3[0], p3[1], p3[2], p3[3]};
    *(intx4*)((char*)d + 3 * WPL) = intx4{p4[0], p4[1], p4[2], p4[3]};
  }
  if (idx < 448) {                           // tabs: bc|bg [128], th [5][64]
    if (idx < 128) tabs[idx] = b_in[idx] + b_gate[idx];
    else {
      const int t = (idx - 128) >> 6, co = (idx - 128) & 63;
      tabs[idx] = powf(tdec[co], (float)t);  // THRESH=1.0
    }
  }
}

// ---- prep: events fp32 [b][tp][c][h][w] -> i8 ch-minor [b][tp][h][w][c] ----
__global__ __launch_bounds__(256) void prep_ev(
    const float* __restrict__ ev, signed char* __restrict__ evb)
{
  const int row  = blockIdx.x * 4 + (threadIdx.x >> 6);  // 0..2559 = (b,tp,h)
  const int w    = threadIdx.x & 63;
  const int b  = row / (TT * HW);
  const int rm = row % (TT * HW);
  const int tp = rm / HW;
  const int h  = rm % HW;
  const float* src = ev + ((size_t)(b * TT + tp) * 64) * PLANE + h * HW + w;
  signed char* dst = evb + ((size_t)((b * TT + tp) * PLANE + h * HW + w)) * 64;
#pragma unroll
  for (int k = 0; k < 8; ++k) {
    unsigned long long pk = 0;
#pragma unroll
    for (int j = 0; j < 8; ++j)
      pk |= (src[(size_t)(k * 8 + j) * PLANE] != 0.f)
              ? (1ull << (8 * j)) : 0ull;
    *(unsigned long long*)(dst + k * 8) = pk;
  }
}

// ---- fused persistent kernel: all 5 steps, LIF state in VGPRs ----
__global__ __launch_bounds__(512, 2) void snn_all(
    const signed char* __restrict__ evb,
    const signed char* __restrict__ Wp,
    const float*       __restrict__ tabs,
    signed char*                    sA,     // spike ping-pong (ch-minor i8)
    signed char*                    sB,
    unsigned*                       flags,  // [256] completed-step counters
    float*             __restrict__ outF)   // d_out [b][co][h][w] fp32
{
  __shared__ signed char U[USIZE];  // [row4][col66][c144]: rows r0-1..r0+2

  const int tid = threadIdx.x;               // 0..511
  const int bid = blockIdx.x;
  const int b   = bid & 7;                   // batch -> XCD (round-robin, perf)
  const int rr  = bid >> 3;                  // row-pair 0..31
  const int r0  = rr * 2;                    // img rows r0, r0+1

  const int lane = tid & 63;
  const int g    = tid >> 6;                 // wave = o-group 0..7
  const int ln   = lane & 15;                // = A's m = B's n (px col in tile)
  const int q    = lane >> 4;                // k-group 0..3

  // staging: 4 rows x 64 cols x 2 x 32B-chunks (events; +spike halo rows 0/3)
  const int srow = tid >> 7;                 // 0..3
  const int scol = (tid >> 1) & 63;
  const int sc2  = tid & 1;
  const int sr   = r0 + srow - 1;
  const bool svalid  = (sr >= 0) && (sr < HW);
  const bool haloldr = svalid && (srow == 0 || srow == 3);
  signed char* du = U + (srow * 66 + scol + 1) * CSTR + sc2 * 32;

  // ---- zero U once: halo col 0/65 + oob rows stay 0 forever (SAME pad) ----
  for (int i = tid; i < USIZE / 16; i += 512) ((intx4*)U)[i] = intx4{0, 0, 0, 0};

  // issue t=0 event loads (land across the zero/barrier)
  intx4 st0 = intx4{0,0,0,0}, st1 = intx4{0,0,0,0};
  if (svalid) {
    const signed char* gs = evb
        + ((size_t)((b * TT + (TT - 1)) * PLANE + sr * HW + scol)) * 64 + sc2 * 32;
    st0 = __builtin_nontemporal_load((const intx4*)gs);
    st1 = __builtin_nontemporal_load((const intx4*)(gs + 16));
  }

  const int laneB = ln * CSTR + q * 16;
  const signed char* wlane = Wp + q * 2048 + (g * 16 + ln) * 16;
  const int co0 = g * 8 + (q & 1) * 4;
  const float4 bc4 = *(const float4*)&tabs[co0];
  const float4 bg4 = *(const float4*)&tabs[64 + co0];

  // dense spike storer role (all 512): one 16B chunk of own rows' spikes
  const int spx  = tid >> 2;                 // 0..127
  const int sprw = spx >> 6;                 // 0,1 -> own rows r0+sprw
  const int spcl = spx & 63;
  const int spch = (tid & 3) * 16;
  const signed char* spu = U + ((1 + sprw) * 66 + spcl + 1) * CSTR + 64 + spch;
  const size_t      spgo = ((size_t)((b * HW + r0 + sprw) * HW + spcl)) * 64 + spch;

  // LIF state in registers: thread-private across all 5 steps, both hf halves
  float vmr[2][4][4], ocr[2][4][4];
#pragma unroll
  for (int hf = 0; hf < 2; ++hf)
#pragma unroll
    for (int tt = 0; tt < 4; ++tt)
#pragma unroll
      for (int r = 0; r < 4; ++r) { vmr[hf][tt][r] = 0.f; ocr[hf][tt][r] = 0.f; }
  uint fmr[2][4];

  __syncthreads();   // U zero complete

  for (int t = 0; t < TT; ++t) {
    // ---- wait for neighbors' step t-1 spikes: 2 polling LANES only ----
    if (t > 0) {
      if (tid < 2) {
        const bool need = tid ? (rr < 31) : (rr > 0);
        if (need) {
          const unsigned* fp = flags + (tid ? bid + 8 : bid - 8);
          for (;;) {
            unsigned fv;
            asm volatile("global_load_dword %0, %1, off sc0 sc1\n\t"
                         "s_waitcnt vmcnt(0)"
                         : "=v"(fv) : "v"(fp) : "memory");
            if (fv >= (unsigned)t) break;
            __builtin_amdgcn_s_sleep(8);
          }
        }
      }
      __syncthreads();   // neighbors' spikes now safe to read
      if (haloldr) {     // halo rows (srow 0/3) from coherent point
        const signed char* ss = (t & 1) ? sB : sA;
        const signed char* gs = ss
            + ((size_t)((b * HW + sr) * HW + scol)) * 64 + sc2 * 32;
        intx4 h0, h1;
        asm volatile("global_load_dwordx4 %0, %2, off sc0 sc1\n\t"
                     "global_load_dwordx4 %1, %2, off offset:16 sc0 sc1\n\t"
                     "s_waitcnt vmcnt(0)"
                     : "=v"(h0), "=v"(h1) : "v"(gs) : "memory");
        *(intx4*)(du + 64)      = h0;
        *(intx4*)(du + 64 + 16) = h1;
      }
    }
    if (svalid) { *(intx4*)du = st0; *(intx4*)(du + 16) = st1; }
    const float4 th4 = *(const float4*)&tabs[128 + t * 64 + co0];
    __syncthreads();   // U ready

    const bool tL = (t == TT - 1);
#pragma unroll
    for (int hf = 0; hf < 2; ++hf) {
      // ---- MFMA: acc[limb][tt] (i32, exact), tile (hf*4+tt), K=128 ----
      intx4 acc1[4], acc2[4], acc3[4], acc4[4];
#pragma unroll
      for (int tt = 0; tt < 4; ++tt) {
        acc1[tt] = intx4{0,0,0,0}; acc2[tt] = intx4{0,0,0,0};
        acc3[tt] = intx4{0,0,0,0}; acc4[tt] = intx4{0,0,0,0};
      }
      for (int tap = 0; tap < 9; ++tap) {
        const int kh = (tap * 11) >> 5;      // tap/3
        const int kw = tap - 3 * kh;
#pragma unroll
        for (int ks = 0; ks < 2; ++ks) {
          const signed char* wp = wlane + (tap * 2 + ks) * 8192;
          const intx4 A1 = *(const intx4*)(wp);
          const intx4 A2 = *(const intx4*)(wp + WPL);
          const intx4 A3 = *(const intx4*)(wp + 2 * WPL);
          const intx4 A4 = *(const intx4*)(wp + 3 * WPL);
          const signed char* ub = U + (hf + kh) * (66 * CSTR) + kw * CSTR + ks * 64 + laneB;
#pragma unroll
          for (int tt = 0; tt < 4; ++tt) {
            const intx4 B = *(const intx4*)(ub + tt * (16 * CSTR));
            acc1[tt] = __builtin_amdgcn_mfma_i32_16x16x64_i8(A1, B, acc1[tt], 0, 0, 0);
            acc2[tt] = __builtin_amdgcn_mfma_i32_16x16x64_i8(A2, B, acc2[tt], 0, 0, 0);
            acc3[tt] = __builtin_amdgcn_mfma_i32_16x16x64_i8(A3, B, acc3[tt], 0, 0, 0);
            acc4[tt] = __builtin_amdgcn_mfma_i32_16x16x64_i8(A4, B, acc4[tt], 0, 0, 0);
          }
        }
      }
      // ---- LIF epilogue COMPUTE only (no U writes yet; U still being read
      // by the other hf pass). D: col=lane&15, row(o')=q*4+reg; lane l
      // (q<2: cur rows) <-> l^32 (gate rows, same co,px).
#pragma unroll
      for (int tt = 0; tt < 4; ++tt) {
        float mine[4];
#pragma unroll
        for (int r = 0; r < 4; ++r)
          mine[r] = fmaf((float)acc1[tt][r], 0x1p-8f,
                    fmaf((float)acc2[tt][r], 0x1p-15f,
                    fmaf((float)acc3[tt][r], 0x1p-22f,
                         (float)acc4[tt][r] * 0x1p-29f)));
        float other[4];
#pragma unroll
        for (int r = 0; r < 4; ++r) other[r] = __shfl_xor(mine[r], 32, 64);
        if (q < 2) {
          uint fm = 0;
#pragma unroll
          for (int r = 0; r < 4; ++r) {
            const float cur  = mine[r] + (&bc4.x)[r];
            const float gp   = other[r] + (&bg4.x)[r];
            const float gate = 1.f / (1.f + expf(-gp));
            const float v    = gate * vmr[hf][tt][r] + cur; // gate*vmem + cur
            const bool fired = (v >= (&th4.x)[r]);          // heaviside
            vmr[hf][tt][r] = fired ? 0.f : v;               // hard reset to 0
            ocr[hf][tt][r] += fired ? 1.f : 0.f;
            fm |= fired ? (1u << (8 * r)) : 0u;
          }
          fmr[hf][tt] = fm;
        }
      }
    }
    __syncthreads();   // ALL U reads done (spike channels about to be rewritten)

    if (!tL) {
      if (q < 2) {     // own spikes into U's contiguous spike bytes
#pragma unroll
        for (int hf = 0; hf < 2; ++hf)
#pragma unroll
          for (int tt = 0; tt < 4; ++tt)
            *(uint*)(U + ((1 + hf) * 66 + tt * 16 + ln + 1) * CSTR + 64 + co0)
                = fmr[hf][tt];
      }
      __syncthreads();   // U spike bytes visible to storer threads
      {                  // dense, fully-coalesced spike publish (8KB/block)
        signed char* sd = (t & 1) ? sA : sB;
        intx4 v = *(const intx4*)spu;        // ds_read_b128
        signed char* gp = sd + spgo;
        asm volatile("global_store_dwordx4 %0, %1, off sc0 sc1"
                     :: "v"(gp), "v"(v) : "memory");
      }
      asm volatile("s_waitcnt vmcnt(0)" ::: "memory");
      __syncthreads();   // every thread's stores drained
      if (tid == 0) {
        unsigned nf = (unsigned)(t + 1);
        unsigned* fp = flags + bid;
        asm volatile("global_store_dword %0, %1, off sc0 sc1"
                     :: "v"(fp), "v"(nf) : "memory");
      }
      // prefetch next step's events
      if (svalid) {
        const signed char* gs = evb
            + ((size_t)((b * TT + (TT - 2 - t)) * PLANE + sr * HW + scol)) * 64
            + sc2 * 32;
        st0 = __builtin_nontemporal_load((const intx4*)gs);
        st1 = __builtin_nontemporal_load((const intx4*)(gs + 16));
      }
    } else {
      // final: mean over T=5, scatter to d_out's [b][co][h][w] (streaming)
      if (q < 2) {
#pragma unroll
        for (int hf = 0; hf < 2; ++hf)
#pragma unroll
          for (int tt = 0; tt < 4; ++tt)
#pragma unroll
            for (int r = 0; r < 4; ++r)
              __builtin_nontemporal_store(ocr[hf][tt][r] * 0.2f,
                  &outF[((size_t)((b * 64 + co0 + r) * HW + (r0 + hf))) * HW
                        + tt * 16 + ln]);
      }
    }
  }
}

extern "C" void kernel_launch(void* const* d_in, const int* in_sizes, int n_in,
                              void* d_out, int out_size, void* d_ws, size_t ws_size,
                              hipStream_t stream) {
  const float* events = (const float*)d_in[0];
  const float* w_in   = (const float*)d_in[1];
  const float* b_in   = (const float*)d_in[2];
  const float* w_gate = (const float*)d_in[3];
  const float* b_gate = (const float*)d_in[4];
  const float* tdec   = (const float*)d_in[5];
  float* out = (float*)d_out;

  char* base = (char*)d_ws;
  unsigned*    flags = (unsigned*)base;                 //      1,024 B
  signed char* sA    = (signed char*)(base + 16777216); //  2,097,152 B (t0 never read)
  signed char* sB    = (signed char*)(base + 18874368); //  2,097,152 B
  signed char* evb   = (signed char*)(base + 20971520); // 10,485,760 B
  signed char* Wp    = (signed char*)(base + 31457280); //    589,824 B (4 limbs)
  float*       tabs  = (float*)(base + 32047104);       //      1,792 B

  hipLaunchKernelGGL(prep_w,  dim3(36),  dim3(256), 0, stream,
                     w_in, w_gate, b_in, b_gate, tdec, Wp, tabs, flags);
  hipLaunchKernelGGL(prep_ev, dim3(640), dim3(256), 0, stream, events, evb);

  void* args[] = {(void*)&evb, (void*)&Wp, (void*)&tabs,
                  (void*)&sA, (void*)&sB, (void*)&flags, (void*)&out};
  hipLaunchCooperativeKernel(reinterpret_cast<const void*>(snn_all),
                             dim3(256), dim3(512), args, 0, stream);
}

// Round 7
// 268.687 us; speedup vs baseline: 1.9878x; 1.2503x over previous
//
#include <hip/hip_runtime.h>
#include <cmath>

// DTASNN embedding via i8 QUAD-limb MFMA implicit conv.
//
// R21 vs R20 (223us; spill theory CONFIRMED directionally: freeing arch regs
// (64->128) cut FETCH 505->172MB, WRITE 378->129MB, dur 405->223us. Residual
// excess ~130/100MB R/W is still fixed-count & symmetric = ~50 dwords/thread
// spilled around the peak-pressure MFMA region: persistent vmr+ocr = 64
// floats must survive a region holding 64 AGPR acc + 16 A-regs + B + addrs):
//  - ocr -> PACKED BYTE COUNTERS: spike counts are exact ints <=5;
//    ocr_pk[2][4] uints accumulate fm directly (fired adds 1<<(8r)); final
//    out = ((ocr_pk>>8r)&255)*0.2f. Bit-exact. Saves 24 arch regs.
//  - vmr -> LDS VM[2*64*68] f32 (34.8KB; pad-68 => float4 state access is
//    2-way bank aliased = free). Thread-private slots, no extra barriers.
//    Saves 32 arch regs. LDS total 72.8KB, still 1 block/CU.
//  Persistent arch state now ~44 regs -> no reason to spill at 256 budget.
// Everything else IDENTICAL to R20 (comms, staging, loop order, arithmetic).
// Arithmetic identical -> bit-exact.
//
// ws: flags 1KB | sA @16M 2MB | sB 2MB | evb 10.5MB | Wp 576KB | tabs

typedef __attribute__((ext_vector_type(4))) int intx4;

#define HW 64
#define TT 5
#define PLANE 4096
#define CSTR 144                  // U px stride bytes (128 ch + 16 pad): odd 9 quads
#define USIZE (4 * 66 * CSTR)     // 38016 B
#define WPL 147456                // per-limb Wp bytes: 9 tap * 2 ks * 4 q * 128 o * 16
#define VMSTR 68                  // floats per px for LDS vmem (64 + 4 pad)
#define VMSZ (128 * VMSTR * 4)    // 34816 B

// ---- prep: weight limbs + bias/threshold tables + flag reset ----
// Wp[limb]: addr = ((tap*2+ks)*4 + q)*2048 + o*16 + j ; o = g*16+i,
// i<8 -> cur row co=g*8+i, i>=8 -> gate row 64+co; c = ks*64 + q*16 + j.
__global__ __launch_bounds__(256) void prep_w(
    const float* __restrict__ w_in, const float* __restrict__ w_gate,
    const float* __restrict__ b_in, const float* __restrict__ b_gate,
    const float* __restrict__ tdec,
    signed char* __restrict__ Wp, float* __restrict__ tabs,
    unsigned* __restrict__ flags)
{
  const int idx = blockIdx.x * 256 + threadIdx.x;
  if (idx < 256) {                           // p2p flags -> coherent point
    unsigned z = 0;
    unsigned* fp = flags + idx;
    asm volatile("global_store_dword %0, %1, off sc0 sc1"
                 :: "v"(fp), "v"(z) : "memory");
  }
  if (idx < 9216) {
    const int o   = idx & 127;
    const int q   = (idx >> 7) & 3;
    const int ks  = (idx >> 9) & 1;
    const int tap = idx >> 10;               // 0..8
    const int g = o >> 4, i = o & 15;
    const int row = (i >> 3) * 64 + g * 8 + (i & 7);
    int p1[4], p2[4], p3[4], p4[4];
#pragma unroll
    for (int wd = 0; wd < 4; ++wd) {
      int v1 = 0, v2 = 0, v3 = 0, v4 = 0;
#pragma unroll
      for (int jb = 0; jb < 4; ++jb) {
        const int j = wd * 4 + jb;
        const int c = ks * 64 + q * 16 + j;
        const float w = (c < 64) ? w_in[(row * 64 + c) * 9 + tap]
                                 : w_gate[(row * 64 + (c - 64)) * 9 + tap];
        float a1 = fminf(fmaxf(rintf(w * 256.f), -127.f), 127.f);
        float r1 = w * 256.f - a1;              // in [-0.5, 0.5]
        float a2 = rintf(r1 * 128.f);
        float r2 = r1 * 128.f - a2;
        float a3 = rintf(r2 * 128.f);
        float r3 = r2 * 128.f - a3;
        float a4 = rintf(r3 * 128.f);
        v1 |= ((int)a1 & 255) << (8 * jb);
        v2 |= ((int)a2 & 255) << (8 * jb);
        v3 |= ((int)a3 & 255) << (8 * jb);
        v4 |= ((int)a4 & 255) << (8 * jb);
      }
      p1[wd] = v1; p2[wd] = v2; p3[wd] = v3; p4[wd] = v4;
    }
    intx4* d = (intx4*)(Wp + (size_t)idx * 16);
    d[0]                          = intx4{p1[0], p1[1], p1[2], p1[3]};
    *(intx4*)((char*)d + WPL)     = intx4{p2[0], p2[1], p2[2], p2[3]};
    *(intx4*)((char*)d + 2 * WPL) = intx4{p3[0], p3[1], p3[2], p3[3]};
    *(intx4*)((char*)d + 3 * WPL) = intx4{p4[0], p4[1], p4[2], p4[3]};
  }
  if (idx < 448) {                           // tabs: bc|bg [128], th [5][64]
    if (idx < 128) tabs[idx] = b_in[idx] + b_gate[idx];
    else {
      const int t = (idx - 128) >> 6, co = (idx - 128) & 63;
      tabs[idx] = powf(tdec[co], (float)t);  // THRESH=1.0
    }
  }
}

// ---- prep: events fp32 [b][tp][c][h][w] -> i8 ch-minor [b][tp][h][w][c] ----
__global__ __launch_bounds__(256) void prep_ev(
    const float* __restrict__ ev, signed char* __restrict__ evb)
{
  const int row  = blockIdx.x * 4 + (threadIdx.x >> 6);  // 0..2559 = (b,tp,h)
  const int w    = threadIdx.x & 63;
  const int b  = row / (TT * HW);
  const int rm = row % (TT * HW);
  const int tp = rm / HW;
  const int h  = rm % HW;
  const float* src = ev + ((size_t)(b * TT + tp) * 64) * PLANE + h * HW + w;
  signed char* dst = evb + ((size_t)((b * TT + tp) * PLANE + h * HW + w)) * 64;
#pragma unroll
  for (int k = 0; k < 8; ++k) {
    unsigned long long pk = 0;
#pragma unroll
    for (int j = 0; j < 8; ++j)
      pk |= (src[(size_t)(k * 8 + j) * PLANE] != 0.f)
              ? (1ull << (8 * j)) : 0ull;
    *(unsigned long long*)(dst + k * 8) = pk;
  }
}

// ---- fused persistent kernel: all 5 steps, vmem in LDS, counts packed ----
__global__ __launch_bounds__(512, 2) void snn_all(
    const signed char* __restrict__ evb,
    const signed char* __restrict__ Wp,
    const float*       __restrict__ tabs,
    signed char*                    sA,     // spike ping-pong (ch-minor i8)
    signed char*                    sB,
    unsigned*                       flags,  // [256] completed-step counters
    float*             __restrict__ outF)   // d_out [b][co][h][w] fp32
{
  __shared__ __align__(16) signed char SM[USIZE + VMSZ];
  signed char* U  = SM;                      // [row4][col66][c144]
  float*       VM = (float*)(SM + USIZE);    // [hf*64+col][68] vmem

  const int tid = threadIdx.x;               // 0..511
  const int bid = blockIdx.x;
  const int b   = bid & 7;                   // batch -> XCD (round-robin, perf)
  const int rr  = bid >> 3;                  // row-pair 0..31
  const int r0  = rr * 2;                    // img rows r0, r0+1

  const int lane = tid & 63;
  const int g    = tid >> 6;                 // wave = o-group 0..7
  const int ln   = lane & 15;                // = A's m = B's n (px col in tile)
  const int q    = lane >> 4;                // k-group 0..3

  // staging: 4 rows x 64 cols x 2 x 32B-chunks (events; +spike halo rows 0/3)
  const int srow = tid >> 7;                 // 0..3
  const int scol = (tid >> 1) & 63;
  const int sc2  = tid & 1;
  const int sr   = r0 + srow - 1;
  const bool svalid  = (sr >= 0) && (sr < HW);
  const bool haloldr = svalid && (srow == 0 || srow == 3);
  signed char* du = U + (srow * 66 + scol + 1) * CSTR + sc2 * 32;

  // ---- zero U+VM once: halo stays 0 forever (SAME pad); vmem starts 0 ----
  for (int i = tid; i < (USIZE + VMSZ) / 16; i += 512)
    ((intx4*)SM)[i] = intx4{0, 0, 0, 0};

  // issue t=0 event loads (land across the zero/barrier)
  intx4 st0 = intx4{0,0,0,0}, st1 = intx4{0,0,0,0};
  if (svalid) {
    const signed char* gs = evb
        + ((size_t)((b * TT + (TT - 1)) * PLANE + sr * HW + scol)) * 64 + sc2 * 32;
    st0 = __builtin_nontemporal_load((const intx4*)gs);
    st1 = __builtin_nontemporal_load((const intx4*)(gs + 16));
  }

  const int laneB = ln * CSTR + q * 16;
  const signed char* wlane = Wp + q * 2048 + (g * 16 + ln) * 16;
  const int co0 = g * 8 + (q & 1) * 4;
  const float4 bc4 = *(const float4*)&tabs[co0];
  const float4 bg4 = *(const float4*)&tabs[64 + co0];

  // dense spike storer role (all 512): one 16B chunk of own rows' spikes
  const int spx  = tid >> 2;                 // 0..127
  const int sprw = spx >> 6;                 // 0,1 -> own rows r0+sprw
  const int spcl = spx & 63;
  const int spch = (tid & 3) * 16;
  const signed char* spu = U + ((1 + sprw) * 66 + spcl + 1) * CSTR + 64 + spch;
  const size_t      spgo = ((size_t)((b * HW + r0 + sprw) * HW + spcl)) * 64 + spch;

  // persistent per-thread state: packed spike counts + per-step fire masks
  uint ocr_pk[2][4] = {{0,0,0,0},{0,0,0,0}};  // byte r = count for co0+r
  uint fmr[2][4];

  __syncthreads();   // LDS zero complete

  for (int t = 0; t < TT; ++t) {
    // ---- wait for neighbors' step t-1 spikes: 2 polling LANES only ----
    if (t > 0) {
      if (tid < 2) {
        const bool need = tid ? (rr < 31) : (rr > 0);
        if (need) {
          const unsigned* fp = flags + (tid ? bid + 8 : bid - 8);
          for (;;) {
            unsigned fv;
            asm volatile("global_load_dword %0, %1, off sc0 sc1\n\t"
                         "s_waitcnt vmcnt(0)"
                         : "=v"(fv) : "v"(fp) : "memory");
            if (fv >= (unsigned)t) break;
            __builtin_amdgcn_s_sleep(8);
          }
        }
      }
      __syncthreads();   // neighbors' spikes now safe to read
      if (haloldr) {     // halo rows (srow 0/3) from coherent point
        const signed char* ss = (t & 1) ? sB : sA;
        const signed char* gs = ss
            + ((size_t)((b * HW + sr) * HW + scol)) * 64 + sc2 * 32;
        intx4 h0, h1;
        asm volatile("global_load_dwordx4 %0, %2, off sc0 sc1\n\t"
                     "global_load_dwordx4 %1, %2, off offset:16 sc0 sc1\n\t"
                     "s_waitcnt vmcnt(0)"
                     : "=v"(h0), "=v"(h1) : "v"(gs) : "memory");
        *(intx4*)(du + 64)      = h0;
        *(intx4*)(du + 64 + 16) = h1;
      }
    }
    if (svalid) { *(intx4*)du = st0; *(intx4*)(du + 16) = st1; }
    const float4 th4 = *(const float4*)&tabs[128 + t * 64 + co0];
    __syncthreads();   // U ready

    const bool tL = (t == TT - 1);
#pragma unroll
    for (int hf = 0; hf < 2; ++hf) {
      // ---- MFMA: acc[limb][tt] (i32, exact), tile (hf*4+tt), K=128 ----
      intx4 acc1[4], acc2[4], acc3[4], acc4[4];
#pragma unroll
      for (int tt = 0; tt < 4; ++tt) {
        acc1[tt] = intx4{0,0,0,0}; acc2[tt] = intx4{0,0,0,0};
        acc3[tt] = intx4{0,0,0,0}; acc4[tt] = intx4{0,0,0,0};
      }
      for (int tap = 0; tap < 9; ++tap) {
        const int kh = (tap * 11) >> 5;      // tap/3
        const int kw = tap - 3 * kh;
#pragma unroll
        for (int ks = 0; ks < 2; ++ks) {
          const signed char* wp = wlane + (tap * 2 + ks) * 8192;
          const intx4 A1 = *(const intx4*)(wp);
          const intx4 A2 = *(const intx4*)(wp + WPL);
          const intx4 A3 = *(const intx4*)(wp + 2 * WPL);
          const intx4 A4 = *(const intx4*)(wp + 3 * WPL);
          const signed char* ub = U + (hf + kh) * (66 * CSTR) + kw * CSTR + ks * 64 + laneB;
#pragma unroll
          for (int tt = 0; tt < 4; ++tt) {
            const intx4 B = *(const intx4*)(ub + tt * (16 * CSTR));
            acc1[tt] = __builtin_amdgcn_mfma_i32_16x16x64_i8(A1, B, acc1[tt], 0, 0, 0);
            acc2[tt] = __builtin_amdgcn_mfma_i32_16x16x64_i8(A2, B, acc2[tt], 0, 0, 0);
            acc3[tt] = __builtin_amdgcn_mfma_i32_16x16x64_i8(A3, B, acc3[tt], 0, 0, 0);
            acc4[tt] = __builtin_amdgcn_mfma_i32_16x16x64_i8(A4, B, acc4[tt], 0, 0, 0);
          }
        }
      }
      // ---- LIF epilogue COMPUTE (vmem in LDS; no U writes yet -- U still
      // read by the other hf pass). D: col=lane&15, row(o')=q*4+reg; lane l
      // (q<2: cur rows) <-> l^32 (gate rows, same co,px).
#pragma unroll
      for (int tt = 0; tt < 4; ++tt) {
        float mine[4];
#pragma unroll
        for (int r = 0; r < 4; ++r)
          mine[r] = fmaf((float)acc1[tt][r], 0x1p-8f,
                    fmaf((float)acc2[tt][r], 0x1p-15f,
                    fmaf((float)acc3[tt][r], 0x1p-22f,
                         (float)acc4[tt][r] * 0x1p-29f)));
        float other[4];
#pragma unroll
        for (int r = 0; r < 4; ++r) other[r] = __shfl_xor(mine[r], 32, 64);
        if (q < 2) {
          float* vp = VM + (hf * 64 + tt * 16 + ln) * VMSTR + co0;
          float4 vm4 = *(const float4*)vp;   // zeros at t=0 (pre-zeroed)
          uint fm = 0;
#pragma unroll
          for (int r = 0; r < 4; ++r) {
            const float cur  = mine[r] + (&bc4.x)[r];
            const float gp   = other[r] + (&bg4.x)[r];
            const float gate = 1.f / (1.f + expf(-gp));
            const float v    = gate * (&vm4.x)[r] + cur;  // gate*vmem + cur
            const bool fired = (v >= (&th4.x)[r]);        // heaviside
            (&vm4.x)[r] = fired ? 0.f : v;                // hard reset to 0
            fm |= fired ? (1u << (8 * r)) : 0u;
          }
          *(float4*)vp = vm4;
          ocr_pk[hf][tt] += fm;              // exact byte counters (<=5)
          fmr[hf][tt] = fm;
        }
      }
    }
    __syncthreads();   // ALL U reads done (spike channels about to be rewritten)

    if (!tL) {
      if (q < 2) {     // own spikes into U's contiguous spike bytes
#pragma unroll
        for (int hf = 0; hf < 2; ++hf)
#pragma unroll
          for (int tt = 0; tt < 4; ++tt)
            *(uint*)(U + ((1 + hf) * 66 + tt * 16 + ln + 1) * CSTR + 64 + co0)
                = fmr[hf][tt];
      }
      __syncthreads();   // U spike bytes visible to storer threads
      {                  // dense, fully-coalesced spike publish (8KB/block)
        signed char* sd = (t & 1) ? sA : sB;
        intx4 v = *(const intx4*)spu;        // ds_read_b128
        signed char* gp = sd + spgo;
        asm volatile("global_store_dwordx4 %0, %1, off sc0 sc1"
                     :: "v"(gp), "v"(v) : "memory");
      }
      asm volatile("s_waitcnt vmcnt(0)" ::: "memory");
      __syncthreads();   // every thread's stores drained
      if (tid == 0) {
        unsigned nf = (unsigned)(t + 1);
        unsigned* fp = flags + bid;
        asm volatile("global_store_dword %0, %1, off sc0 sc1"
                     :: "v"(fp), "v"(nf) : "memory");
      }
      // prefetch next step's events
      if (svalid) {
        const signed char* gs = evb
            + ((size_t)((b * TT + (TT - 2 - t)) * PLANE + sr * HW + scol)) * 64
            + sc2 * 32;
        st0 = __builtin_nontemporal_load((const intx4*)gs);
        st1 = __builtin_nontemporal_load((const intx4*)(gs + 16));
      }
    } else {
      // final: mean over T=5 from packed counts -> d_out [b][co][h][w]
      if (q < 2) {
#pragma unroll
        for (int hf = 0; hf < 2; ++hf)
#pragma unroll
          for (int tt = 0; tt < 4; ++tt)
#pragma unroll
            for (int r = 0; r < 4; ++r)
              __builtin_nontemporal_store(
                  (float)((ocr_pk[hf][tt] >> (8 * r)) & 255u) * 0.2f,
                  &outF[((size_t)((b * 64 + co0 + r) * HW + (r0 + hf))) * HW
                        + tt * 16 + ln]);
      }
    }
  }
}

extern "C" void kernel_launch(void* const* d_in, const int* in_sizes, int n_in,
                              void* d_out, int out_size, void* d_ws, size_t ws_size,
                              hipStream_t stream) {
  const float* events = (const float*)d_in[0];
  const float* w_in   = (const float*)d_in[1];
  const float* b_in   = (const float*)d_in[2];
  const float* w_gate = (const float*)d_in[3];
  const float* b_gate = (const float*)d_in[4];
  const float* tdec   = (const float*)d_in[5];
  float* out = (float*)d_out;

  char* base = (char*)d_ws;
  unsigned*    flags = (unsigned*)base;                 //      1,024 B
  signed char* sA    = (signed char*)(base + 16777216); //  2,097,152 B (t0 never read)
  signed char* sB    = (signed char*)(base + 18874368); //  2,097,152 B
  signed char* evb   = (signed char*)(base + 20971520); // 10,485,760 B
  signed char* Wp    = (signed char*)(base + 31457280); //    589,824 B (4 limbs)
  float*       tabs  = (float*)(base + 32047104);       //      1,792 B

  hipLaunchKernelGGL(prep_w,  dim3(36),  dim3(256), 0, stream,
                     w_in, w_gate, b_in, b_gate, tdec, Wp, tabs, flags);
  hipLaunchKernelGGL(prep_ev, dim3(640), dim3(256), 0, stream, events, evb);

  void* args[] = {(void*)&evb, (void*)&Wp, (void*)&tabs,
                  (void*)&sA, (void*)&sB, (void*)&flags, (void*)&out};
  hipLaunchCooperativeKernel(reinterpret_cast<const void*>(snn_all),
                             dim3(256), dim3(512), args, 0, stream);
}